// Round 1
// baseline (494.699 us; speedup 1.0000x reference)
//
#include <hip/hip_runtime.h>

#define EPS 1e-5f

__device__ __forceinline__ float ht(float x){ return fminf(fmaxf(x, -1.f), 1.f); }
__device__ __forceinline__ float sgn(float v){ return (v > 0.f) ? 1.f : ((v < 0.f) ? -1.f : 0.f); }

// ---------------- Kernel 1: conv1(K=17,s=2,p=8) + BN + hardtanh + maxpool2 ----------------
// x[B,16384] -> out1[B,16,4096]
__global__ __launch_bounds__(256) void k1(const float* __restrict__ x,
        const float* __restrict__ w1, const float* __restrict__ g1,
        const float* __restrict__ b1, const float* __restrict__ m1,
        const float* __restrict__ v1, float* __restrict__ out1){
    __shared__ __align__(16) float xs[2064];
    __shared__ float wsh[16*17];
    __shared__ float sc[16], sh[16];
    const int b   = blockIdx.x >> 3;          // 8 tiles of 512 pooled per b
    const int p0  = (blockIdx.x & 7) * 512;
    const int tid = threadIdx.x;
    const int base = 4*p0 - 8;                // x index of local 0
    for(int i = tid; i < 2064; i += 256){
        int g = base + i;
        xs[i] = (g >= 0 && g < 16384) ? x[b*16384 + g] : 0.f;
    }
    for(int i = tid; i < 272; i += 256) wsh[i] = w1[i];
    if(tid < 16){
        float s = g1[tid] * rsqrtf(v1[tid] + EPS);
        sc[tid] = s; sh[tid] = b1[tid] - m1[tid]*s;
    }
    __syncthreads();
    for(int it = 0; it < 8; ++it){
        int idx  = it*256 + tid;
        int g128 = idx & 127;                 // pooled group (4 outputs)
        int oc   = idx >> 7;                  // 0..15
        float xr[32];
        #pragma unroll
        for(int i = 0; i < 8; ++i)
            *(float4*)&xr[4*i] = *(const float4*)&xs[16*g128 + 4*i];
        float wv[17];
        #pragma unroll
        for(int k = 0; k < 17; ++k) wv[k] = wsh[oc*17 + k];
        float s = sc[oc], h = sh[oc];
        float4 o; float* op = &o.x;
        #pragma unroll
        for(int j = 0; j < 4; ++j){
            float a0 = 0.f, a1 = 0.f;
            #pragma unroll
            for(int k = 0; k < 17; ++k){
                a0 += wv[k]*xr[4*j + k];
                a1 += wv[k]*xr[4*j + 2 + k];
            }
            op[j] = fmaxf(ht(a0*s + h), ht(a1*s + h));
        }
        *(float4*)&out1[(b*16 + oc)*4096 + p0 + 4*g128] = o;
    }
}

// ---------------- Kernel 2: conv2(sign w, K=9,s=2,p=4) + BN + hardtanh + maxpool2 --------
// out1[B,16,4096] -> out2[B,32,1024]
__global__ __launch_bounds__(256) void k2(const float* __restrict__ in,
        const float* __restrict__ w2, const float* __restrict__ g2,
        const float* __restrict__ be2, const float* __restrict__ m2,
        const float* __restrict__ v2, float* __restrict__ out2){
    __shared__ __align__(16) float a[16*520];   // tile rows, stride 520 (519 used)
    __shared__ float wsh[32*16*9];
    __shared__ float sc[32], sh[32];
    const int b   = blockIdx.x >> 3;            // 8 tiles of 128 pooled per b
    const int p0  = (blockIdx.x & 7) * 128;
    const int tid = threadIdx.x;
    const int base = 4*p0 - 4;
    for(int ic = 0; ic < 16; ++ic){
        const float* row = &in[(b*16 + ic)*4096];
        for(int j = tid; j < 519; j += 256){
            int g = base + j;
            a[ic*520 + j] = (g >= 0 && g < 4096) ? row[g] : 0.f;
        }
    }
    for(int i = tid; i < 4608; i += 256) wsh[i] = sgn(w2[i]);
    if(tid < 32){
        float s = g2[tid] * rsqrtf(v2[tid] + EPS);
        sc[tid] = s; sh[tid] = be2[tid] - m2[tid]*s;
    }
    __syncthreads();
    for(int it = 0; it < 2; ++it){
        int idx = it*256 + tid;
        int g   = idx & 31;                     // pooled group (4 outputs)
        int ocp = idx >> 5;                     // 0..15 -> oc pair
        int oc0 = 2*ocp;
        float acc[2][4][2] = {};
        for(int ic = 0; ic < 16; ++ic){
            float xr[24];
            #pragma unroll
            for(int i = 0; i < 6; ++i)
                *(float4*)&xr[4*i] = *(const float4*)&a[ic*520 + 16*g + 4*i];
            #pragma unroll
            for(int o = 0; o < 2; ++o){
                const float* wp = &wsh[((oc0 + o)*16 + ic)*9];
                #pragma unroll
                for(int k = 0; k < 9; ++k){
                    float w = wp[k];
                    #pragma unroll
                    for(int j = 0; j < 4; ++j){
                        acc[o][j][0] += w*xr[4*j + k];
                        acc[o][j][1] += w*xr[4*j + 2 + k];
                    }
                }
            }
        }
        #pragma unroll
        for(int o = 0; o < 2; ++o){
            int oc = oc0 + o;
            float s = sc[oc], h = sh[oc];
            float4 y; float* yp = &y.x;
            #pragma unroll
            for(int j = 0; j < 4; ++j)
                yp[j] = fmaxf(ht(acc[o][j][0]*s + h), ht(acc[o][j][1]*s + h));
            *(float4*)&out2[(b*32 + oc)*1024 + p0 + 4*g] = y;
        }
    }
}

// ---------------- Kernel 3: conv3(sign w, K=5,s=2,p=2) + BN + hardtanh + maxpool2 --------
// out2[B,32,1024] -> out3[B,64,256]   (grid: b x 4 p-tiles x 2 oc-halves)
__global__ __launch_bounds__(256) void k3(const float* __restrict__ in,
        const float* __restrict__ w3, const float* __restrict__ g3,
        const float* __restrict__ be3, const float* __restrict__ m3,
        const float* __restrict__ v3, float* __restrict__ out3){
    __shared__ __align__(16) float a[32*260];   // 259 used per row
    __shared__ float wsh[32*32*5];              // this block's 32 ocs
    __shared__ float sc[32], sh[32];
    const int b      = blockIdx.x >> 3;
    const int rem    = blockIdx.x & 7;
    const int p0     = (rem & 3) * 64;
    const int ocbase = (rem >> 2) * 32;
    const int tid = threadIdx.x;
    const int base = 4*p0 - 2;
    for(int ic = 0; ic < 32; ++ic){
        const float* row = &in[(b*32 + ic)*1024];
        for(int j = tid; j < 259; j += 256){
            int g = base + j;
            a[ic*260 + j] = (g >= 0 && g < 1024) ? row[g] : 0.f;
        }
    }
    for(int i = tid; i < 5120; i += 256){
        int oloc = i / 160;
        int r    = i - oloc*160;
        wsh[i] = sgn(w3[(ocbase + oloc)*160 + r]);
    }
    if(tid < 32){
        int c = ocbase + tid;
        float s = g3[c] * rsqrtf(v3[c] + EPS);
        sc[tid] = s; sh[tid] = be3[c] - m3[c]*s;
    }
    __syncthreads();
    const int g    = tid & 15;                  // pooled group (4 outputs)
    const int oc0l = (tid >> 4) * 2;            // local oc pair
    float acc[2][4][2] = {};
    for(int ic = 0; ic < 32; ++ic){
        float xr[20];
        #pragma unroll
        for(int i = 0; i < 5; ++i)
            *(float4*)&xr[4*i] = *(const float4*)&a[ic*260 + 16*g + 4*i];
        #pragma unroll
        for(int o = 0; o < 2; ++o){
            const float* wp = &wsh[((oc0l + o)*32 + ic)*5];
            #pragma unroll
            for(int k = 0; k < 5; ++k){
                float w = wp[k];
                #pragma unroll
                for(int j = 0; j < 4; ++j){
                    acc[o][j][0] += w*xr[4*j + k];
                    acc[o][j][1] += w*xr[4*j + 2 + k];
                }
            }
        }
    }
    #pragma unroll
    for(int o = 0; o < 2; ++o){
        int ol = oc0l + o;
        float s = sc[ol], h = sh[ol];
        float4 y; float* yp = &y.x;
        #pragma unroll
        for(int j = 0; j < 4; ++j)
            yp[j] = fmaxf(ht(acc[o][j][0]*s + h), ht(acc[o][j][1]*s + h));
        *(float4*)&out3[(b*64 + ocbase + ol)*256 + p0 + 4*g] = y;
    }
}

// ---------------- Kernel 4: mean over L + concat rms + fc1 + hardtanh + fc2 --------------
// out3[B,64,256] -> out[B,2]
__global__ __launch_bounds__(256) void k4(const float* __restrict__ p3,
        const float* __restrict__ rms, const float* __restrict__ fc1w,
        const float* __restrict__ fc1b, const float* __restrict__ fc2w,
        const float* __restrict__ fc2b, float* __restrict__ out){
    __shared__ float part[256];
    __shared__ float feat[64];
    __shared__ float hbuf[32];
    const int b = blockIdx.x;
    const int tid = threadIdx.x;
    const int oc = tid >> 2, q = tid & 3;
    const float* row = &p3[(b*64 + oc)*256 + q*64];
    float s = 0.f;
    for(int j = 0; j < 16; ++j){
        float4 v = *(const float4*)&row[4*j];
        s += v.x + v.y + v.z + v.w;
    }
    part[tid] = s;
    __syncthreads();
    if(tid < 64)
        feat[tid] = (part[4*tid] + part[4*tid+1] + part[4*tid+2] + part[4*tid+3]) * (1.f/256.f);
    __syncthreads();
    if(tid < 32){
        float acc = fc1b[tid];
        const float* w = &fc1w[tid*65];
        #pragma unroll
        for(int c = 0; c < 64; ++c) acc += w[c]*feat[c];
        acc += w[64]*rms[b];
        hbuf[tid] = ht(acc);
    }
    __syncthreads();
    if(tid < 2){
        float acc = fc2b[tid];
        const float* w = &fc2w[tid*32];
        #pragma unroll
        for(int j = 0; j < 32; ++j) acc += w[j]*hbuf[j];
        out[b*2 + tid] = acc;
    }
}

extern "C" void kernel_launch(void* const* d_in, const int* in_sizes, int n_in,
                              void* d_out, int out_size, void* d_ws, size_t ws_size,
                              hipStream_t stream){
    (void)in_sizes; (void)n_in; (void)out_size; (void)ws_size;
    const float* x    = (const float*)d_in[0];
    const float* rms  = (const float*)d_in[1];
    const float* w1   = (const float*)d_in[2];
    const float* g1   = (const float*)d_in[3];
    const float* b1   = (const float*)d_in[4];
    const float* m1   = (const float*)d_in[5];
    const float* v1   = (const float*)d_in[6];
    const float* w2   = (const float*)d_in[7];
    const float* g2   = (const float*)d_in[8];
    const float* b2   = (const float*)d_in[9];
    const float* m2   = (const float*)d_in[10];
    const float* v2   = (const float*)d_in[11];
    const float* w3   = (const float*)d_in[12];
    const float* g3   = (const float*)d_in[13];
    const float* b3   = (const float*)d_in[14];
    const float* m3   = (const float*)d_in[15];
    const float* v3   = (const float*)d_in[16];
    const float* fc1w = (const float*)d_in[17];
    const float* fc1b = (const float*)d_in[18];
    const float* fc2w = (const float*)d_in[19];
    const float* fc2b = (const float*)d_in[20];
    float* out  = (float*)d_out;

    float* out1 = (float*)d_ws;                 // 256*16*4096 = 16,777,216 floats
    float* out2 = out1 + 256*16*4096;           // 256*32*1024 =  8,388,608 floats
    float* out3 = out2 + 256*32*1024;           // 256*64*256  =  4,194,304 floats

    k1<<<2048, 256, 0, stream>>>(x,    w1, g1, b1, m1, v1, out1);
    k2<<<2048, 256, 0, stream>>>(out1, w2, g2, b2, m2, v2, out2);
    k3<<<2048, 256, 0, stream>>>(out2, w3, g3, b3, m3, v3, out3);
    k4<<<256,  256, 0, stream>>>(out3, rms, fc1w, fc1b, fc2w, fc2b, out);
}

// Round 2
// 362.599 us; speedup vs baseline: 1.3643x; 1.3643x over previous
//
#include <hip/hip_runtime.h>

#define EPS 1e-5f

__device__ __forceinline__ float ht(float x){ return fminf(fmaxf(x, -1.f), 1.f); }
__device__ __forceinline__ float sgn(float v){ return (v > 0.f) ? 1.f : ((v < 0.f) ? -1.f : 0.f); }

// ---------------- Kernel 1: conv1(K=17,s=2,p=8) + BN + hardtanh + maxpool2 ----------------
// x[B,16384] -> out1[B,16,4096]
// Lane mapping: oc fast (16), g slow -> LDS x reads broadcast 16-way (2-way bank alias, free),
// weight reads stride-17 (odd) -> conflict-free.
__global__ __launch_bounds__(256) void k1(const float* __restrict__ x,
        const float* __restrict__ w1, const float* __restrict__ g1,
        const float* __restrict__ b1, const float* __restrict__ m1,
        const float* __restrict__ v1, float* __restrict__ out1){
    __shared__ __align__(16) float xs[2064];
    __shared__ float wsh[16*17];
    __shared__ float sc[16], sh[16];
    const int b   = blockIdx.x >> 3;          // 8 tiles of 512 pooled per b
    const int p0  = (blockIdx.x & 7) * 512;
    const int tid = threadIdx.x;
    const int base = 4*p0 - 8;                // x index of local 0
    for(int i = tid; i < 2064; i += 256){
        int g = base + i;
        xs[i] = (g >= 0 && g < 16384) ? x[b*16384 + g] : 0.f;
    }
    for(int i = tid; i < 272; i += 256) wsh[i] = w1[i];
    if(tid < 16){
        float s = g1[tid] * rsqrtf(v1[tid] + EPS);
        sc[tid] = s; sh[tid] = b1[tid] - m1[tid]*s;
    }
    __syncthreads();
    for(int it = 0; it < 8; ++it){
        int idx  = it*256 + tid;
        int oc   = idx & 15;                  // FAST: output channel
        int g128 = idx >> 4;                  // SLOW: pooled group (4 outputs)
        float xr[32];
        #pragma unroll
        for(int i = 0; i < 8; ++i)
            *(float4*)&xr[4*i] = *(const float4*)&xs[16*g128 + 4*i];
        float wv[17];
        #pragma unroll
        for(int k = 0; k < 17; ++k) wv[k] = wsh[oc*17 + k];
        float s = sc[oc], h = sh[oc];
        float4 o; float* op = &o.x;
        #pragma unroll
        for(int j = 0; j < 4; ++j){
            float a0 = 0.f, a1 = 0.f;
            #pragma unroll
            for(int k = 0; k < 17; ++k){
                a0 += wv[k]*xr[4*j + k];
                a1 += wv[k]*xr[4*j + 2 + k];
            }
            op[j] = fmaxf(ht(a0*s + h), ht(a1*s + h));
        }
        *(float4*)&out1[(b*16 + oc)*4096 + p0 + 4*g128] = o;
    }
}

// ---------------- Kernel 2: conv2(sign w, K=9,s=2,p=4) + BN + hardtanh + maxpool2 --------
// out1[B,16,4096] -> out2[B,32,1024]
// Lane mapping: oc-pair fast (16), g slow. Weight rows padded to 145 floats (odd stride).
__global__ __launch_bounds__(256) void k2(const float* __restrict__ in,
        const float* __restrict__ w2, const float* __restrict__ g2,
        const float* __restrict__ be2, const float* __restrict__ m2,
        const float* __restrict__ v2, float* __restrict__ out2){
    __shared__ __align__(16) float a[16*520];   // tile rows, stride 520 (519 used)
    __shared__ float wsh[32*145];               // padded: 144 used per oc row
    __shared__ float sc[32], sh[32];
    const int b   = blockIdx.x >> 3;            // 8 tiles of 128 pooled per b
    const int p0  = (blockIdx.x & 7) * 128;
    const int tid = threadIdx.x;
    const int base = 4*p0 - 4;
    for(int ic = 0; ic < 16; ++ic){
        const float* row = &in[(b*16 + ic)*4096];
        for(int j = tid; j < 519; j += 256){
            int g = base + j;
            a[ic*520 + j] = (g >= 0 && g < 4096) ? row[g] : 0.f;
        }
    }
    for(int i = tid; i < 32*145; i += 256){
        int ol = i / 145;
        int r  = i - ol*145;
        if(r < 144) wsh[i] = sgn(w2[ol*144 + r]);
    }
    if(tid < 32){
        float s = g2[tid] * rsqrtf(v2[tid] + EPS);
        sc[tid] = s; sh[tid] = be2[tid] - m2[tid]*s;
    }
    __syncthreads();
    for(int it = 0; it < 2; ++it){
        int idx = it*256 + tid;
        int ocp = idx & 15;                     // FAST: oc pair
        int g   = idx >> 4;                     // SLOW: pooled group (4 outputs), 0..31
        int oc0 = 2*ocp;
        float acc[2][4][2] = {};
        for(int ic = 0; ic < 16; ++ic){
            float xr[24];
            #pragma unroll
            for(int i = 0; i < 6; ++i)
                *(float4*)&xr[4*i] = *(const float4*)&a[ic*520 + 16*g + 4*i];
            #pragma unroll
            for(int o = 0; o < 2; ++o){
                const float* wp = &wsh[(oc0 + o)*145 + ic*9];
                #pragma unroll
                for(int k = 0; k < 9; ++k){
                    float w = wp[k];
                    #pragma unroll
                    for(int j = 0; j < 4; ++j){
                        acc[o][j][0] += w*xr[4*j + k];
                        acc[o][j][1] += w*xr[4*j + 2 + k];
                    }
                }
            }
        }
        #pragma unroll
        for(int o = 0; o < 2; ++o){
            int oc = oc0 + o;
            float s = sc[oc], h = sh[oc];
            float4 y; float* yp = &y.x;
            #pragma unroll
            for(int j = 0; j < 4; ++j)
                yp[j] = fmaxf(ht(acc[o][j][0]*s + h), ht(acc[o][j][1]*s + h));
            *(float4*)&out2[(b*32 + oc)*1024 + p0 + 4*g] = y;
        }
    }
}

// ---------------- Kernel 3: conv3(sign w, K=5,s=2,p=2) + BN + hardtanh + maxpool2 --------
// out2[B,32,1024] -> out3[B,64,256]   (grid: b x 4 p-tiles x 2 oc-halves)
// Lane mapping: oc-pair fast (16), g slow. Weight rows padded to 161 floats (odd stride).
__global__ __launch_bounds__(256) void k3(const float* __restrict__ in,
        const float* __restrict__ w3, const float* __restrict__ g3,
        const float* __restrict__ be3, const float* __restrict__ m3,
        const float* __restrict__ v3, float* __restrict__ out3){
    __shared__ __align__(16) float a[32*260];   // 259 used per row
    __shared__ float wsh[32*161];               // padded: 160 used per local-oc row
    __shared__ float sc[32], sh[32];
    const int b      = blockIdx.x >> 3;
    const int rem    = blockIdx.x & 7;
    const int p0     = (rem & 3) * 64;
    const int ocbase = (rem >> 2) * 32;
    const int tid = threadIdx.x;
    const int base = 4*p0 - 2;
    for(int ic = 0; ic < 32; ++ic){
        const float* row = &in[(b*32 + ic)*1024];
        for(int j = tid; j < 259; j += 256){
            int g = base + j;
            a[ic*260 + j] = (g >= 0 && g < 1024) ? row[g] : 0.f;
        }
    }
    for(int i = tid; i < 32*161; i += 256){
        int ol = i / 161;
        int r  = i - ol*161;
        if(r < 160) wsh[i] = sgn(w3[(ocbase + ol)*160 + r]);
    }
    if(tid < 32){
        int c = ocbase + tid;
        float s = g3[c] * rsqrtf(v3[c] + EPS);
        sc[tid] = s; sh[tid] = be3[c] - m3[c]*s;
    }
    __syncthreads();
    const int ocp  = tid & 15;                  // FAST: oc pair
    const int g    = tid >> 4;                  // SLOW: pooled group (4 outputs), 0..15
    const int oc0l = 2*ocp;
    float acc[2][4][2] = {};
    for(int ic = 0; ic < 32; ++ic){
        float xr[20];
        #pragma unroll
        for(int i = 0; i < 5; ++i)
            *(float4*)&xr[4*i] = *(const float4*)&a[ic*260 + 16*g + 4*i];
        #pragma unroll
        for(int o = 0; o < 2; ++o){
            const float* wp = &wsh[(oc0l + o)*161 + ic*5];
            #pragma unroll
            for(int k = 0; k < 5; ++k){
                float w = wp[k];
                #pragma unroll
                for(int j = 0; j < 4; ++j){
                    acc[o][j][0] += w*xr[4*j + k];
                    acc[o][j][1] += w*xr[4*j + 2 + k];
                }
            }
        }
    }
    #pragma unroll
    for(int o = 0; o < 2; ++o){
        int ol = oc0l + o;
        float s = sc[ol], h = sh[ol];
        float4 y; float* yp = &y.x;
        #pragma unroll
        for(int j = 0; j < 4; ++j)
            yp[j] = fmaxf(ht(acc[o][j][0]*s + h), ht(acc[o][j][1]*s + h));
        *(float4*)&out3[(b*64 + ocbase + ol)*256 + p0 + 4*g] = y;
    }
}

// ---------------- Kernel 4: mean over L + concat rms + fc1 + hardtanh + fc2 --------------
// out3[B,64,256] -> out[B,2]
__global__ __launch_bounds__(256) void k4(const float* __restrict__ p3,
        const float* __restrict__ rms, const float* __restrict__ fc1w,
        const float* __restrict__ fc1b, const float* __restrict__ fc2w,
        const float* __restrict__ fc2b, float* __restrict__ out){
    __shared__ float part[256];
    __shared__ float feat[64];
    __shared__ float hbuf[32];
    const int b = blockIdx.x;
    const int tid = threadIdx.x;
    const int oc = tid >> 2, q = tid & 3;
    const float* row = &p3[(b*64 + oc)*256 + q*64];
    float s = 0.f;
    for(int j = 0; j < 16; ++j){
        float4 v = *(const float4*)&row[4*j];
        s += v.x + v.y + v.z + v.w;
    }
    part[tid] = s;
    __syncthreads();
    if(tid < 64)
        feat[tid] = (part[4*tid] + part[4*tid+1] + part[4*tid+2] + part[4*tid+3]) * (1.f/256.f);
    __syncthreads();
    if(tid < 32){
        float acc = fc1b[tid];
        const float* w = &fc1w[tid*65];
        #pragma unroll
        for(int c = 0; c < 64; ++c) acc += w[c]*feat[c];
        acc += w[64]*rms[b];
        hbuf[tid] = ht(acc);
    }
    __syncthreads();
    if(tid < 2){
        float acc = fc2b[tid];
        const float* w = &fc2w[tid*32];
        #pragma unroll
        for(int j = 0; j < 32; ++j) acc += w[j]*hbuf[j];
        out[b*2 + tid] = acc;
    }
}

extern "C" void kernel_launch(void* const* d_in, const int* in_sizes, int n_in,
                              void* d_out, int out_size, void* d_ws, size_t ws_size,
                              hipStream_t stream){
    (void)in_sizes; (void)n_in; (void)out_size; (void)ws_size;
    const float* x    = (const float*)d_in[0];
    const float* rms  = (const float*)d_in[1];
    const float* w1   = (const float*)d_in[2];
    const float* g1   = (const float*)d_in[3];
    const float* b1   = (const float*)d_in[4];
    const float* m1   = (const float*)d_in[5];
    const float* v1   = (const float*)d_in[6];
    const float* w2   = (const float*)d_in[7];
    const float* g2   = (const float*)d_in[8];
    const float* b2   = (const float*)d_in[9];
    const float* m2   = (const float*)d_in[10];
    const float* v2   = (const float*)d_in[11];
    const float* w3   = (const float*)d_in[12];
    const float* g3   = (const float*)d_in[13];
    const float* b3   = (const float*)d_in[14];
    const float* m3   = (const float*)d_in[15];
    const float* v3   = (const float*)d_in[16];
    const float* fc1w = (const float*)d_in[17];
    const float* fc1b = (const float*)d_in[18];
    const float* fc2w = (const float*)d_in[19];
    const float* fc2b = (const float*)d_in[20];
    float* out  = (float*)d_out;

    float* out1 = (float*)d_ws;                 // 256*16*4096 = 16,777,216 floats
    float* out2 = out1 + 256*16*4096;           // 256*32*1024 =  8,388,608 floats
    float* out3 = out2 + 256*32*1024;           // 256*64*256  =  4,194,304 floats

    k1<<<2048, 256, 0, stream>>>(x,    w1, g1, b1, m1, v1, out1);
    k2<<<2048, 256, 0, stream>>>(out1, w2, g2, b2, m2, v2, out2);
    k3<<<2048, 256, 0, stream>>>(out2, w3, g3, b3, m3, v3, out3);
    k4<<<256,  256, 0, stream>>>(out3, rms, fc1w, fc1b, fc2w, fc2b, out);
}

// Round 3
// 236.887 us; speedup vs baseline: 2.0883x; 1.5307x over previous
//
#include <hip/hip_runtime.h>

#define EPS 1e-5f

__device__ __forceinline__ float ht(float x){ return fminf(fmaxf(x, -1.f), 1.f); }
__device__ __forceinline__ float sgn(float v){ return (v > 0.f) ? 1.f : ((v < 0.f) ? -1.f : 0.f); }

// ---------------- Kernel 1: conv1(K=17,s=2,p=8) + BN + hardtanh + maxpool2 ----------------
// x[B,16384] -> out1[B,16,4096].  512 thr, weights hoisted to regs, float4 staging.
__global__ __launch_bounds__(512, 6) void k1(const float* __restrict__ x,
        const float* __restrict__ w1, const float* __restrict__ g1,
        const float* __restrict__ b1, const float* __restrict__ m1,
        const float* __restrict__ v1, float* __restrict__ out1){
    __shared__ __align__(16) float xs[2064];
    __shared__ __align__(16) float wsh[272];
    __shared__ float sc[16], sh[16];
    const int b   = blockIdx.x >> 3;          // 8 tiles of 512 pooled per b
    const int p0  = (blockIdx.x & 7) * 512;
    const int tid = threadIdx.x;
    const int base = 4*p0 - 8;                // x index of LDS slot 0 (16B aligned)
    const float* xrow = &x[b*16384];
    for(int i = tid; i < 516; i += 512){
        int g0 = base + 4*i;
        float4 v = make_float4(0.f,0.f,0.f,0.f);
        if(g0 >= 0 && g0 <= 16380) v = *(const float4*)&xrow[g0];  // full-in or full-out
        *(float4*)&xs[4*i] = v;
    }
    if(tid < 68) *(float4*)&wsh[4*tid] = *(const float4*)&w1[4*tid];
    if(tid < 16){
        float s = g1[tid] * rsqrtf(v1[tid] + EPS);
        sc[tid] = s; sh[tid] = b1[tid] - m1[tid]*s;
    }
    __syncthreads();
    const int oc = tid & 15;                  // constant per thread -> hoist weights
    float wv[17];
    #pragma unroll
    for(int k = 0; k < 17; ++k) wv[k] = wsh[oc*17 + k];
    const float s = sc[oc], h = sh[oc];
    #pragma unroll
    for(int it = 0; it < 4; ++it){
        int gq = (tid >> 4) + it*32;          // 0..127
        float xr[32];
        #pragma unroll
        for(int i = 0; i < 8; ++i)
            *(float4*)&xr[4*i] = *(const float4*)&xs[16*gq + 4*i];
        float4 o; float* op = &o.x;
        #pragma unroll
        for(int j = 0; j < 4; ++j){
            float a0 = 0.f, a1 = 0.f;
            #pragma unroll
            for(int k = 0; k < 17; ++k){
                a0 += wv[k]*xr[4*j + k];
                a1 += wv[k]*xr[4*j + 2 + k];
            }
            op[j] = fmaxf(ht(a0*s + h), ht(a1*s + h));
        }
        *(float4*)&out1[(b*16 + oc)*4096 + p0 + 4*gq] = o;
    }
}

// ---------------- Kernel 2: conv2(sign w, K=9,s=2,p=4) + BN + hardtanh + maxpool2 --------
// out1[B,16,4096] -> out2[B,32,1024].  512 thr (1 pass), float4 staging, 3 blocks/CU.
__global__ __launch_bounds__(512, 6) void k2(const float* __restrict__ in,
        const float* __restrict__ w2, const float* __restrict__ g2,
        const float* __restrict__ be2, const float* __restrict__ m2,
        const float* __restrict__ v2, float* __restrict__ out2){
    __shared__ __align__(16) float a[16*520];   // row j holds in[4*p0-4+j], stride 520
    __shared__ float wsh[32*145];               // padded odd stride
    __shared__ float sc[32], sh[32];
    const int b   = blockIdx.x >> 3;            // 8 tiles of 128 pooled per b
    const int p0  = (blockIdx.x & 7) * 128;
    const int tid = threadIdx.x;
    const int base = 4*p0 - 4;                  // 16B aligned
    for(int i = tid; i < 2080; i += 512){       // 16 rows x 130 float4
        int row = i / 130, m = i - row*130;
        int g0  = base + 4*m;
        float4 v = make_float4(0.f,0.f,0.f,0.f);
        if(g0 >= 0 && g0 <= 4092) v = *(const float4*)&in[(b*16 + row)*4096 + g0];
        *(float4*)&a[row*520 + 4*m] = v;
    }
    for(int i = tid; i < 1152; i += 512){       // 32 oc x 36 float4
        int ol = i / 36, m = i - ol*36;
        float4 v = *(const float4*)&w2[ol*144 + 4*m];
        float* wp = &wsh[ol*145 + 4*m];
        wp[0] = sgn(v.x); wp[1] = sgn(v.y); wp[2] = sgn(v.z); wp[3] = sgn(v.w);
    }
    if(tid < 32){
        float s = g2[tid] * rsqrtf(v2[tid] + EPS);
        sc[tid] = s; sh[tid] = be2[tid] - m2[tid]*s;
    }
    __syncthreads();
    const int ocp = tid & 15;                   // FAST: oc pair
    const int g   = tid >> 4;                   // SLOW: pooled quad, 0..31
    const int oc0 = 2*ocp;
    float acc[2][4][2] = {};
    for(int ic = 0; ic < 16; ++ic){
        float xr[24];
        #pragma unroll
        for(int i = 0; i < 6; ++i)
            *(float4*)&xr[4*i] = *(const float4*)&a[ic*520 + 16*g + 4*i];
        #pragma unroll
        for(int o = 0; o < 2; ++o){
            const float* wp = &wsh[(oc0 + o)*145 + ic*9];
            #pragma unroll
            for(int k = 0; k < 9; ++k){
                float w = wp[k];
                #pragma unroll
                for(int j = 0; j < 4; ++j){
                    acc[o][j][0] += w*xr[4*j + k];
                    acc[o][j][1] += w*xr[4*j + 2 + k];
                }
            }
        }
    }
    #pragma unroll
    for(int o = 0; o < 2; ++o){
        int oc = oc0 + o;
        float s = sc[oc], h = sh[oc];
        float4 y; float* yp = &y.x;
        #pragma unroll
        for(int j = 0; j < 4; ++j)
            yp[j] = fmaxf(ht(acc[o][j][0]*s + h), ht(acc[o][j][1]*s + h));
        *(float4*)&out2[(b*32 + oc)*1024 + p0 + 4*g] = y;
    }
}

// ---------------- Kernel 3: conv3(sign w, K=5,s=2,p=2) + BN + hardtanh + maxpool2 --------
// out2[B,32,1024] -> out3[B,64,256].  64 oc x 64 pooled per block, 512 thr,
// signed-char weights in LDS (45.3 KB total -> 3 blocks/CU = 24 waves).
__global__ __launch_bounds__(512, 6) void k3(const float* __restrict__ in,
        const float* __restrict__ w3, const float* __restrict__ g3,
        const float* __restrict__ be3, const float* __restrict__ m3,
        const float* __restrict__ v3, float* __restrict__ out3){
    __shared__ __align__(16) float xs3[32*268]; // row j holds in[4*p0-4+j], 264 used
    __shared__ __align__(4) signed char wb[64*164]; // 160 used per oc row
    __shared__ float sc[64], sh[64];
    const int b   = blockIdx.x >> 2;            // 4 tiles of 64 pooled per b
    const int p0  = (blockIdx.x & 3) * 64;
    const int tid = threadIdx.x;
    const int base = 4*p0 - 4;                  // 16B aligned
    for(int i = tid; i < 2112; i += 512){       // 32 rows x 66 float4
        int row = i / 66, m = i - row*66;
        int g0  = base + 4*m;
        float4 v = make_float4(0.f,0.f,0.f,0.f);
        if(g0 >= 0 && g0 <= 1020) v = *(const float4*)&in[(b*32 + row)*1024 + g0];
        *(float4*)&xs3[row*268 + 4*m] = v;
    }
    for(int i = tid; i < 2560; i += 512){       // 64 oc x 40 float4 -> char4
        int oc = i / 40, m = i - oc*40;
        float4 v = *(const float4*)&w3[oc*160 + 4*m];
        char4 c;
        c.x = (signed char)(int)sgn(v.x); c.y = (signed char)(int)sgn(v.y);
        c.z = (signed char)(int)sgn(v.z); c.w = (signed char)(int)sgn(v.w);
        *(char4*)&wb[oc*164 + 4*m] = c;
    }
    if(tid < 64){
        float s = g3[tid] * rsqrtf(v3[tid] + EPS);
        sc[tid] = s; sh[tid] = be3[tid] - m3[tid]*s;
    }
    __syncthreads();
    const int ocp = tid & 31;                   // FAST: oc pair (64 oc)
    const int g   = tid >> 5;                   // SLOW: pooled quad, 0..15
    const int oc0 = 2*ocp;
    float acc[2][4][2] = {};
    for(int ic = 0; ic < 32; ++ic){
        float xr[24];                           // x[4p0-4 + 16g .. +23]
        #pragma unroll
        for(int i = 0; i < 6; ++i)
            *(float4*)&xr[4*i] = *(const float4*)&xs3[ic*268 + 16*g + 4*i];
        #pragma unroll
        for(int o = 0; o < 2; ++o){
            const signed char* wp = &wb[(oc0 + o)*164 + ic*5];
            #pragma unroll
            for(int k = 0; k < 5; ++k){
                float w = (float)wp[k];
                #pragma unroll
                for(int j = 0; j < 4; ++j){
                    acc[o][j][0] += w*xr[4*j + k + 2];
                    acc[o][j][1] += w*xr[4*j + k + 4];
                }
            }
        }
    }
    #pragma unroll
    for(int o = 0; o < 2; ++o){
        int oc = oc0 + o;
        float s = sc[oc], h = sh[oc];
        float4 y; float* yp = &y.x;
        #pragma unroll
        for(int j = 0; j < 4; ++j)
            yp[j] = fmaxf(ht(acc[o][j][0]*s + h), ht(acc[o][j][1]*s + h));
        *(float4*)&out3[(b*64 + oc)*256 + p0 + 4*g] = y;
    }
}

// ---------------- Kernel 4: mean over L + concat rms + fc1 + hardtanh + fc2 --------------
// out3[B,64,256] -> out[B,2]
__global__ __launch_bounds__(256) void k4(const float* __restrict__ p3,
        const float* __restrict__ rms, const float* __restrict__ fc1w,
        const float* __restrict__ fc1b, const float* __restrict__ fc2w,
        const float* __restrict__ fc2b, float* __restrict__ out){
    __shared__ float part[256];
    __shared__ float feat[64];
    __shared__ float hbuf[32];
    const int b = blockIdx.x;
    const int tid = threadIdx.x;
    const int oc = tid >> 2, q = tid & 3;
    const float* row = &p3[(b*64 + oc)*256 + q*64];
    float s = 0.f;
    for(int j = 0; j < 16; ++j){
        float4 v = *(const float4*)&row[4*j];
        s += v.x + v.y + v.z + v.w;
    }
    part[tid] = s;
    __syncthreads();
    if(tid < 64)
        feat[tid] = (part[4*tid] + part[4*tid+1] + part[4*tid+2] + part[4*tid+3]) * (1.f/256.f);
    __syncthreads();
    if(tid < 32){
        float acc = fc1b[tid];
        const float* w = &fc1w[tid*65];
        #pragma unroll
        for(int c = 0; c < 64; ++c) acc += w[c]*feat[c];
        acc += w[64]*rms[b];
        hbuf[tid] = ht(acc);
    }
    __syncthreads();
    if(tid < 2){
        float acc = fc2b[tid];
        const float* w = &fc2w[tid*32];
        #pragma unroll
        for(int j = 0; j < 32; ++j) acc += w[j]*hbuf[j];
        out[b*2 + tid] = acc;
    }
}

extern "C" void kernel_launch(void* const* d_in, const int* in_sizes, int n_in,
                              void* d_out, int out_size, void* d_ws, size_t ws_size,
                              hipStream_t stream){
    (void)in_sizes; (void)n_in; (void)out_size; (void)ws_size;
    const float* x    = (const float*)d_in[0];
    const float* rms  = (const float*)d_in[1];
    const float* w1   = (const float*)d_in[2];
    const float* g1   = (const float*)d_in[3];
    const float* b1   = (const float*)d_in[4];
    const float* m1   = (const float*)d_in[5];
    const float* v1   = (const float*)d_in[6];
    const float* w2   = (const float*)d_in[7];
    const float* g2   = (const float*)d_in[8];
    const float* b2   = (const float*)d_in[9];
    const float* m2   = (const float*)d_in[10];
    const float* v2   = (const float*)d_in[11];
    const float* w3   = (const float*)d_in[12];
    const float* g3   = (const float*)d_in[13];
    const float* b3   = (const float*)d_in[14];
    const float* m3   = (const float*)d_in[15];
    const float* v3   = (const float*)d_in[16];
    const float* fc1w = (const float*)d_in[17];
    const float* fc1b = (const float*)d_in[18];
    const float* fc2w = (const float*)d_in[19];
    const float* fc2b = (const float*)d_in[20];
    float* out  = (float*)d_out;

    float* out1 = (float*)d_ws;                 // 256*16*4096 = 16,777,216 floats
    float* out2 = out1 + 256*16*4096;           // 256*32*1024 =  8,388,608 floats
    float* out3 = out2 + 256*32*1024;           // 256*64*256  =  4,194,304 floats

    k1<<<2048, 512, 0, stream>>>(x,    w1, g1, b1, m1, v1, out1);
    k2<<<2048, 512, 0, stream>>>(out1, w2, g2, b2, m2, v2, out2);
    k3<<<1024, 512, 0, stream>>>(out2, w3, g3, b3, m3, v3, out3);
    k4<<<256,  256, 0, stream>>>(out3, rms, fc1w, fc1b, fc2w, fc2b, out);
}